// Round 1
// baseline (321.843 us; speedup 1.0000x reference)
//
#include <hip/hip_runtime.h>

#define BB 128
#define SS 512
#define DD 1024
#define START_ID 30522
#define END_ID   30523

// Kernel 1: per-row span find + euph[b,:] = sum of inputs[b, start+1..end-1, :].
// One block per row; thread t owns d = 4t..4t+3 (float4, fully coalesced).
// Block 0 also zeroes the M buffer (ws is re-poisoned to 0xAA before every call).
__global__ void span_euph_kernel(const float* __restrict__ inputs,
                                 const int* __restrict__ ids,
                                 float* __restrict__ euph,
                                 float* __restrict__ Mbuf) {
    const int b = blockIdx.x;
    const int t = threadIdx.x;

    if (b == 0) {
        for (int i = t; i < 2 * DD; i += 256) Mbuf[i] = 0.0f;
    }

    __shared__ int s_start, s_end;
    for (int s = t; s < SS; s += 256) {
        int id = ids[b * SS + s];
        if (id == START_ID) s_start = s;   // exactly one per row
        if (id == END_ID)   s_end = s;     // exactly one per row
    }
    __syncthreads();
    const int st = s_start;
    const int en = s_end;

    float4 acc = make_float4(0.f, 0.f, 0.f, 0.f);
    const size_t rowbase = (size_t)b * SS * DD + 4 * t;
    for (int s = st + 1; s < en; ++s) {
        float4 v = *(const float4*)(inputs + rowbase + (size_t)s * DD);
        acc.x += v.x; acc.y += v.y; acc.z += v.z; acc.w += v.w;
    }
    *(float4*)(euph + (size_t)b * DD + 4 * t) = acc;
}

// Kernel 2: M[j,k] = sum_d W2[j,d] * W1[d,k]   (j in {0,1})
// 256 blocks: bid&3 selects k-chunk of 256, bid>>2 selects a 16-wide d slice.
// Coalesced W1 reads (consecutive k across threads); 2 atomicAdds/thread.
__global__ void build_M_kernel(const float* __restrict__ W1,
                               const float* __restrict__ W2,
                               float* __restrict__ Mbuf) {
    const int bid = blockIdx.x;
    const int t = threadIdx.x;
    const int k = (bid & 3) * 256 + t;
    const int d0 = (bid >> 2) * 16;

    float m0 = 0.f, m1 = 0.f;
    for (int i = 0; i < 16; ++i) {
        int d = d0 + i;
        float w1 = W1[(size_t)d * DD + k];
        m0 += W2[d]      * w1;
        m1 += W2[DD + d] * w1;
    }
    atomicAdd(&Mbuf[k],      m0);
    atomicAdd(&Mbuf[DD + k], m1);
}

// Kernel 3: out[b,j] = euph[b,:]·M[j,:] + W2[j,:]·b1 + b2[j]
__global__ void out_kernel(const float* __restrict__ euph,
                           const float* __restrict__ Mbuf,
                           const float* __restrict__ W2,
                           const float* __restrict__ b1,
                           const float* __restrict__ b2,
                           float* __restrict__ out) {
    const int b = blockIdx.x;
    const int t = threadIdx.x;

    float s0 = 0.f, s1 = 0.f, c0 = 0.f, c1 = 0.f;
    for (int k = t; k < DD; k += 256) {
        float e = euph[(size_t)b * DD + k];
        s0 += e * Mbuf[k];
        s1 += e * Mbuf[DD + k];
        float bv = b1[k];
        c0 += W2[k]      * bv;
        c1 += W2[DD + k] * bv;
    }

    __shared__ float r0[256], r1[256], r2[256], r3[256];
    r0[t] = s0; r1[t] = s1; r2[t] = c0; r3[t] = c1;
    __syncthreads();
    for (int off = 128; off >= 1; off >>= 1) {
        if (t < off) {
            r0[t] += r0[t + off];
            r1[t] += r1[t + off];
            r2[t] += r2[t + off];
            r3[t] += r3[t + off];
        }
        __syncthreads();
    }
    if (t == 0) {
        out[2 * b]     = r0[0] + r2[0] + b2[0];
        out[2 * b + 1] = r1[0] + r3[0] + b2[1];
    }
}

extern "C" void kernel_launch(void* const* d_in, const int* in_sizes, int n_in,
                              void* d_out, int out_size, void* d_ws, size_t ws_size,
                              hipStream_t stream) {
    const float* inputs = (const float*)d_in[0];
    const int*   ids    = (const int*)d_in[1];
    const float* W1     = (const float*)d_in[2];
    const float* b1     = (const float*)d_in[3];
    const float* W2     = (const float*)d_in[4];
    const float* b2     = (const float*)d_in[5];
    float* out = (float*)d_out;

    float* euph = (float*)d_ws;                 // B*D floats = 512 KiB
    float* Mbuf = euph + (size_t)BB * DD;       // 2*D floats

    span_euph_kernel<<<BB, 256, 0, stream>>>(inputs, ids, euph, Mbuf);
    build_M_kernel<<<256, 256, 0, stream>>>(W1, W2, Mbuf);
    out_kernel<<<BB, 256, 0, stream>>>(euph, Mbuf, W2, b1, b2, out);
}